// Round 16
// baseline (206.458 us; speedup 1.0000x reference)
//
#include <hip/hip_runtime.h>

// Problem constants
#define B_ 4
#define S_ 2048
#define H_ 16
#define D_ 64
#define E_ 1024
#define M_ 8192   // B_*S_

typedef __attribute__((ext_vector_type(8))) __bf16 bf16x8;
typedef __attribute__((ext_vector_type(4))) __bf16 bf16x4;
typedef __attribute__((ext_vector_type(4))) float f32x4;
typedef __attribute__((ext_vector_type(16))) float f32x16;

// async global->LDS, 16B per lane; LDS base must be wave-uniform
__device__ __forceinline__ void gload_lds16(const void* g, void* l) {
  __builtin_amdgcn_global_load_lds(
      (const __attribute__((address_space(1))) unsigned int*)g,
      (__attribute__((address_space(3))) unsigned int*)l, 16, 0, 0);
}

__device__ __forceinline__ unsigned pk2(float a, float b) {
  union { __bf16 h; unsigned short u; } ua, ub;
  ua.h = (__bf16)a; ub.h = (__bf16)b;
  return ((unsigned)ub.u << 16) | (unsigned)ua.u;
}

// ---------------- fp32 -> bf16 convert, 3 tensors in one dispatch ----------
// (round-15 forensics: fusing this cvt into GEMM staging costs MORE than the
// 24us it saves — reg-staging exposes load latency and multiplies fp32 A
// traffic by tile reuse. Keep the separate HBM-roofline cvt pass.)
__global__ void cvt_all(const float* __restrict__ q, const float* __restrict__ k,
                        const float* __restrict__ v, __bf16* __restrict__ Aq,
                        __bf16* __restrict__ Ak, __bf16* __restrict__ Av) {
  const int y = blockIdx.y;
  const float* src = (y == 0) ? q : (y == 1) ? k : v;
  __bf16* dst = (y == 0) ? Aq : (y == 1) ? Ak : Av;
  const int i = blockIdx.x * blockDim.x + threadIdx.x;
  const float4 vv = ((const float4*)src)[i];
  bf16x4 o;
  o.x = (__bf16)vv.x; o.y = (__bf16)vv.y; o.z = (__bf16)vv.z; o.w = (__bf16)vv.w;
  ((bf16x4*)dst)[i] = o;
}

// ---------------- weight packing into B^T layout [n][k] bf16, one dispatch --
__global__ void pack_all(const float* __restrict__ wq, const float* __restrict__ wk,
                         const float* __restrict__ wv, const float* __restrict__ wo,
                         __bf16* __restrict__ Bq, __bf16* __restrict__ Bk,
                         __bf16* __restrict__ Bv, __bf16* __restrict__ Bo) {
  const int y = blockIdx.y;
  const int idx = blockIdx.x * 256 + threadIdx.x;  // 1024*1024 total
  const int n = idx >> 10, kk = idx & 1023;
  if (y < 3) {
    const float* w = (y == 0) ? wq : (y == 1) ? wk : wv;
    __bf16* out = (y == 0) ? Bq : (y == 1) ? Bk : Bv;
    out[idx] = (__bf16)w[((size_t)(n >> 6) << 16) + (kk << 6) + (n & 63)];
  } else {
    Bo[idx] = (__bf16)wo[((size_t)kk << 10) + n];
  }
}

// ---------------- 2-phase double-buffered staging (T3-minimum) -------------
// stage one 128x64 A-tile + 128x64 B-tile into buffer `buf` for K-step kt.
#define GEMM_STAGE(A_, Bt_, kt_, buf_)                                        \
  {                                                                           \
    const int kb_ = (kt_) * 64;                                               \
    _Pragma("unroll") for (int j = 0; j < 4; ++j) {                           \
      const int ci = (j * 4 + w) * 64 + l;                                    \
      const int row = ci >> 3;                                                \
      const int c = (ci & 7) ^ (row & 7);                                     \
      gload_lds16((A_) + (size_t)(m0 + row) * 1024 + kb_ + c * 8,             \
                  As[buf_] + (j * 4 + w) * 512);                              \
      gload_lds16((Bt_) + (size_t)(n0 + row) * 1024 + kb_ + c * 8,            \
                  Bs[buf_] + (j * 4 + w) * 512);                              \
    }                                                                         \
  }

#define GEMM_COMPUTE(buf_)                                                    \
  _Pragma("unroll") for (int kk = 0; kk < 64; kk += 32) {                     \
    bf16x8 af[4], bfr[4];                                                     \
    _Pragma("unroll") for (int f = 0; f < 4; ++f) {                           \
      const int ra = (w >> 1) * 64 + f * 16 + (l & 15);                       \
      const int ca = ((kk >> 3) + (l >> 4)) ^ (ra & 7);                       \
      af[f] = *(const bf16x8*)(As[buf_] + ra * 64 + ca * 8);                  \
      const int rb = (w & 1) * 64 + f * 16 + (l & 15);                        \
      const int cb = ((kk >> 3) + (l >> 4)) ^ (rb & 7);                       \
      bfr[f] = *(const bf16x8*)(Bs[buf_] + rb * 64 + cb * 8);                 \
    }                                                                         \
    _Pragma("unroll") for (int mf = 0; mf < 4; ++mf)                          \
        _Pragma("unroll") for (int nf = 0; nf < 4; ++nf)                      \
            acc[mf][nf] = __builtin_amdgcn_mfma_f32_16x16x32_bf16(            \
                af[mf], bfr[nf], acc[mf][nf], 0, 0, 0);                       \
  }

#define GEMM_PIPE(A_, Bt_)                                                    \
  GEMM_STAGE(A_, Bt_, 0, 0);                                                  \
  int cur = 0;                                                                \
  for (int kt = 0; kt < 16; ++kt) {                                           \
    __builtin_amdgcn_sched_barrier(0);                                        \
    asm volatile("s_waitcnt vmcnt(0)" ::: "memory");                          \
    __builtin_amdgcn_s_barrier();                                             \
    __builtin_amdgcn_sched_barrier(0);                                        \
    if (kt + 1 < 16) GEMM_STAGE(A_, Bt_, kt + 1, cur ^ 1);                    \
    GEMM_COMPUTE(cur);                                                        \
    cur ^= 1;                                                                 \
  }

// ---------------- merged q+k projection GEMM (grid-y select, 2-D grid) -----
__global__ __launch_bounds__(256) void gemm_qk(
    const __bf16* __restrict__ Aq, const __bf16* __restrict__ Ak,
    const __bf16* __restrict__ Bq, const __bf16* __restrict__ Bk,
    const float* __restrict__ bq, const float* __restrict__ bk,
    __bf16* __restrict__ qhb, __bf16* __restrict__ khb) {
  __shared__ __bf16 As[2][128 * 64];
  __shared__ __bf16 Bs[2][128 * 64];
  const int t = threadIdx.x;
  const int w = t >> 6, l = t & 63;
  const int isK = blockIdx.y >> 3;
  const __bf16* A = isK ? Ak : Aq;
  const __bf16* Bt = isK ? Bk : Bq;
  const float* bias = isK ? bk : bq;
  __bf16* C = isK ? khb : qhb;
  const int m0 = blockIdx.x * 128, n0 = (blockIdx.y & 7) * 128;
  f32x4 acc[4][4] = {};

  GEMM_PIPE(A, Bt);

#pragma unroll
  for (int mf = 0; mf < 4; ++mf)
#pragma unroll
    for (int nf = 0; nf < 4; ++nf)
#pragma unroll
      for (int r = 0; r < 4; ++r) {
        const int gm = m0 + (w >> 1) * 64 + mf * 16 + (l >> 4) * 4 + r;
        const int gn = n0 + (w & 1) * 64 + nf * 16 + (l & 15);
        const float val = acc[mf][nf][r] + bias[gn];
        C[(((size_t)(gm >> 11) * H_ + (gn >> 6)) * S_ + (gm & 2047)) * D_ + (gn & 63)] =
            (__bf16)val;
      }
}

// ---------------- bf16 MFMA GEMM: C[M,N] = A[M,K] * Bt[N,K]^T + bias -------
// MODE 1: scatter bf16 to [B,H,D,S] (A is weights, Bt is activations), bias[gm]
// MODE 2: fp32 C[gm*1024+gn] = acc + bias[gn]
template <int MODE>
__global__ __launch_bounds__(256) void gemm_bt(const __bf16* __restrict__ A,
                                               const __bf16* __restrict__ Bt,
                                               const float* __restrict__ bias,
                                               void* __restrict__ Cout) {
  __shared__ __bf16 As[2][128 * 64];
  __shared__ __bf16 Bs[2][128 * 64];
  const int t = threadIdx.x;
  const int w = t >> 6, l = t & 63;
  const int m0 = blockIdx.x * 128, n0 = blockIdx.y * 128;
  f32x4 acc[4][4] = {};

  GEMM_PIPE(A, Bt);

#pragma unroll
  for (int mf = 0; mf < 4; ++mf) {
#pragma unroll
    for (int nf = 0; nf < 4; ++nf) {
#pragma unroll
      for (int r = 0; r < 4; ++r) {
        const int gm = m0 + (w >> 1) * 64 + mf * 16 + (l >> 4) * 4 + r;
        const int gn = n0 + (w & 1) * 64 + nf * 16 + (l & 15);
        const float val = acc[mf][nf][r] + ((MODE == 1) ? bias[gm] : bias[gn]);
        if constexpr (MODE == 1) {
          ((__bf16*)Cout)[(((size_t)(gn >> 11) * H_ + (gm >> 6)) * D_ + (gm & 63)) * S_ + (gn & 2047)] =
              (__bf16)val;
        } else {
          ((float*)Cout)[(size_t)gm * 1024 + gn] = val;
        }
      }
    }
  }
}

// ---------------- attn staging helpers -------------------------------------
__device__ __forceinline__ void stage_k128(const __bf16* __restrict__ Kb, int kt,
                                           __bf16* Kdst, int t, int w) {
#pragma unroll
  for (int j = 0; j < 4; ++j) {
    const int ci = j * 256 + t;
    const int row = ci >> 3;
    const int sc = (ci & 7) ^ (row & 7);
    gload_lds16(Kb + (size_t)(kt * 128 + row) * D_ + sc * 8, Kdst + j * 2048 + w * 512);
  }
}
__device__ __forceinline__ void stage_v64(const __bf16* __restrict__ Vb, int col0,
                                          __bf16* Vdst, int t, int w) {
#pragma unroll
  for (int j = 0; j < 2; ++j) {
    const int ci = j * 256 + t;
    const int row = ci >> 3;
    const int sc = (ci & 7) ^ (row & 7);
    gload_lds16(Vb + (size_t)row * S_ + col0 + sc * 8, Vdst + j * 2048 + w * 512);
  }
}

// ---------------- fused causal flash attention (v8, round-12 verbatim) -----
// grid (64 bh, 8 pr). Round-14 forensics: same-bh blocks are ids bh+64*pr,
// 64%8==0 -> same XCD -> K/V L2 locality. Do NOT swap the grid axes
// (tried: FETCH 27->147MB, +5us).
__global__ __launch_bounds__(256, 2) void attn_fused(const __bf16* __restrict__ qh,
                                                     const __bf16* __restrict__ kh,
                                                     const __bf16* __restrict__ vT,
                                                     __bf16* __restrict__ concat,
                                                     const int* __restrict__ use_mask_p) {
  __shared__ __bf16 Ks[2][128 * 64];     // [buf][kv 128][e 64]
  __shared__ __bf16 Vs[2][2][64 * 64];   // [buf][sub][e 64][kv 64]
  const int t = threadIdx.x, w = t >> 6, l = t & 63;
  const int lo = l & 31, hi = l >> 5;
  const int bh = blockIdx.x, pr = blockIdx.y;  // pr in 0..7
  const int usemask = *use_mask_p;
  const __bf16* Qb = qh + (size_t)bh * S_ * D_;
  const __bf16* Kb = kh + (size_t)bh * S_ * D_;
  const __bf16* Vb = vT + (size_t)bh * D_ * S_;
  const int b = bh >> 4, hh = bh & 15;
  constexpr float CEXP = 0.125f * 1.4426950408889634f;  // scale*log2(e)

  bf16x8 ones;
#pragma unroll
  for (int i = 0; i < 8; ++i) ones[i] = (__bf16)1.0f;

  int cur = 0;
  for (int half = 0; half < 2; ++half) {
    const int qt = half ? (15 - pr) : pr;       // 16 q-tiles of 128 rows
    const int qrow0 = qt * 128 + w * 32;
    const int nkt = usemask ? (qt + 1) : (S_ / 128);        // 128-kv steps
    const int ktw = usemask ? (2 * qt + (w >> 1)) : (1 << 30);  // 64-kv units

    // Q B-frags (col=lo, k=e contiguous 8 at hi*8), loop-invariant
    bf16x8 qf[4];
#pragma unroll
    for (int ks = 0; ks < 4; ++ks)
      qf[ks] = *(const bf16x8*)(Qb + (size_t)(qrow0 + lo) * D_ + ks * 16 + hi * 8);

    float m = -3e38f;
    f32x16 lsacc = {};
    f32x16 o0 = {}, o1 = {};

    // prologue: stage tile 0 into buf[cur]
    stage_k128(Kb, 0, &Ks[cur][0], t, w);
    stage_v64(Vb, 0, &Vs[cur][0][0], t, w);
    stage_v64(Vb, 64, &Vs[cur][1][0], t, w);

    for (int kt = 0; kt < nkt; ++kt) {
      __builtin_amdgcn_sched_barrier(0);
      asm volatile("s_waitcnt vmcnt(0)" ::: "memory");
      __builtin_amdgcn_s_barrier();
      __builtin_amdgcn_sched_barrier(0);

      // stage next 128-kv tile into the other buffer (overlaps this compute)
      if (kt + 1 < nkt) {
        const int nxt = cur ^ 1;
        stage_k128(Kb, kt + 1, &Ks[nxt][0], t, w);
        stage_v64(Vb, (kt + 1) * 128, &Vs[nxt][0][0], t, w);
        stage_v64(Vb, (kt + 1) * 128 + 64, &Vs[nxt][1][0], t, w);
      }

#pragma unroll
      for (int sub = 0; sub < 2; ++sub) {
        const int st = 2 * kt + sub;          // 64-kv sub-tile index
        if (st <= ktw) {
          const __bf16* Ksub = &Ks[cur][sub * 64 * 64];
          const __bf16* Vsub = &Vs[cur][sub][0];

          // ---- S^T = K * Q^T ----
          f32x16 s0 = {}, s1 = {};
          __builtin_amdgcn_s_setprio(1);
#pragma unroll
          for (int ks = 0; ks < 4; ++ks) {
            const int ch = ((ks << 1) | hi) ^ (lo & 7);
            const bf16x8 k0 = *(const bf16x8*)(Ksub + lo * 64 + ch * 8);
            const bf16x8 k1 = *(const bf16x8*)(Ksub + (32 + lo) * 64 + ch * 8);
            s0 = __builtin_amdgcn_mfma_f32_32x32x16_bf16(k0, qf[ks], s0, 0, 0, 0);
            s1 = __builtin_amdgcn_mfma_f32_32x32x16_bf16(k1, qf[ks], s1, 0, 0, 0);
          }
          __builtin_amdgcn_s_setprio(0);

          if (usemask && st == ktw) {  // diagonal sub-tile (raw-score mask)
            const int qloc = ((w & 1) << 5) + lo;
#pragma unroll
            for (int r = 0; r < 16; ++r) {
              const int kv0 = (r & 3) + 8 * (r >> 2) + 4 * hi;
              if (kv0 > qloc) s0[r] = -1e30f;
              if (kv0 + 32 > qloc) s1[r] = -1e30f;
            }
          }

          // ---- online softmax, lane-local; pair-shfl only when rescaling ----
          float pm = s0[0];
#pragma unroll
          for (int r = 1; r < 16; ++r) pm = fmaxf(pm, s0[r]);
#pragma unroll
          for (int r = 0; r < 16; ++r) pm = fmaxf(pm, s1[r]);

          if (!__all(pm - m <= 64.0f)) {  // defer-max (8 logit units)
            const float pmp = fmaxf(pm, __shfl_xor(pm, 32));  // pair-consistent
            const float mn = fmaxf(m, pmp);
            const float al = __builtin_amdgcn_exp2f((m - mn) * CEXP);
            m = mn;
            lsacc[0] *= al;
            o0 *= al;
            o1 *= al;
          }
          const float mneg = -m * CEXP;  // exp2(s*C - m*C) via fma

          // exp + pack into 4-value blocks (2 words each): W[mf][j]
          unsigned W0[4][2], W1[4][2];
#pragma unroll
          for (int j = 0; j < 4; ++j) {
            float p0 = __builtin_amdgcn_exp2f(__builtin_fmaf(s0[4 * j + 0], CEXP, mneg));
            float p1 = __builtin_amdgcn_exp2f(__builtin_fmaf(s0[4 * j + 1], CEXP, mneg));
            float p2 = __builtin_amdgcn_exp2f(__builtin_fmaf(s0[4 * j + 2], CEXP, mneg));
            float p3 = __builtin_amdgcn_exp2f(__builtin_fmaf(s0[4 * j + 3], CEXP, mneg));
            W0[j][0] = pk2(p0, p1);
            W0[j][1] = pk2(p2, p3);
            float q0 = __builtin_amdgcn_exp2f(__builtin_fmaf(s1[4 * j + 0], CEXP, mneg));
            float q1 = __builtin_amdgcn_exp2f(__builtin_fmaf(s1[4 * j + 1], CEXP, mneg));
            float q2 = __builtin_amdgcn_exp2f(__builtin_fmaf(s1[4 * j + 2], CEXP, mneg));
            float q3 = __builtin_amdgcn_exp2f(__builtin_fmaf(s1[4 * j + 3], CEXP, mneg));
            W1[j][0] = pk2(q0, q1);
            W1[j][1] = pk2(q2, q3);
          }

          // build P^T B-frags in-register: pairwise permlane32_swap (proven)
          bf16x8 pa[4];
#pragma unroll
          for (int ks = 0; ks < 4; ++ks) {
            const int c = ks & 1;
            unsigned x0, x1, y0, y1;
            if ((ks >> 1) == 0) {
              x0 = W0[2 * c][0]; x1 = W0[2 * c][1];
              y0 = W0[2 * c + 1][0]; y1 = W0[2 * c + 1][1];
            } else {
              x0 = W1[2 * c][0]; x1 = W1[2 * c][1];
              y0 = W1[2 * c + 1][0]; y1 = W1[2 * c + 1][1];
            }
            asm volatile("v_permlane32_swap_b32 %0, %1" : "+v"(x0), "+v"(y0));
            asm volatile("v_permlane32_swap_b32 %0, %1" : "+v"(x1), "+v"(y1));
            union { unsigned u[4]; bf16x8 v; } uu;
            uu.u[0] = x0; uu.u[1] = x1; uu.u[2] = y0; uu.u[3] = y1;
            pa[ks] = uu.v;
          }

          // ---- O^T += V^T * P^T ; ls += 1^T * P^T (column sums) ----
          __builtin_amdgcn_s_setprio(1);
#pragma unroll
          for (int ks = 0; ks < 4; ++ks) {
            const int ch = ((ks << 1) | hi) ^ (lo & 7);
            const bf16x8 v0 = *(const bf16x8*)(Vsub + lo * 64 + ch * 8);
            const bf16x8 v1 = *(const bf16x8*)(Vsub + (32 + lo) * 64 + ch * 8);
            o0 = __builtin_amdgcn_mfma_f32_32x32x16_bf16(v0, pa[ks], o0, 0, 0, 0);
            o1 = __builtin_amdgcn_mfma_f32_32x32x16_bf16(v1, pa[ks], o1, 0, 0, 0);
            lsacc = __builtin_amdgcn_mfma_f32_32x32x16_bf16(ones, pa[ks], lsacc, 0, 0, 0);
          }
          __builtin_amdgcn_s_setprio(0);
        }
      }
      cur ^= 1;
    }

    // epilogue: out[qrow][h*64 + e] = o^T[e][q]/ls  (ls = lsacc[0], col=q)
    const float inv = 1.0f / lsacc[0];
    const size_t rowbase = ((size_t)(b * S_ + qrow0 + lo)) * E_ + hh * 64;
#pragma unroll
    for (int rr = 0; rr < 4; ++rr) {
      bf16x4 v0, v1;
#pragma unroll
      for (int bb = 0; bb < 4; ++bb) {
        v0[bb] = (__bf16)(o0[4 * rr + bb] * inv);
        v1[bb] = (__bf16)(o1[4 * rr + bb] * inv);
      }
      *(bf16x4*)(concat + rowbase + 8 * rr + 4 * hi) = v0;
      *(bf16x4*)(concat + rowbase + 32 + 8 * rr + 4 * hi) = v1;
    }
  }
}

// ---------------- launch ----------------
extern "C" void kernel_launch(void* const* d_in, const int* in_sizes, int n_in,
                              void* d_out, int out_size, void* d_ws, size_t ws_size,
                              hipStream_t stream) {
  const float* q = (const float*)d_in[0];
  const float* k = (const float*)d_in[1];
  const float* v = (const float*)d_in[2];
  const float* wq = (const float*)d_in[3];
  const float* bq = (const float*)d_in[4];
  const float* wk = (const float*)d_in[5];
  const float* bk = (const float*)d_in[6];
  const float* wv = (const float*)d_in[7];
  const float* bv = (const float*)d_in[8];
  const float* wo = (const float*)d_in[9];
  const float* bo = (const float*)d_in[10];
  const int* use_mask = (const int*)d_in[11];
  (void)in_sizes; (void)n_in; (void)out_size; (void)ws_size;

  char* ws = (char*)d_ws;
  __bf16* Aq = (__bf16*)ws;                       // [8192,1024] bf16
  __bf16* Ak = Aq + (size_t)M_ * E_;
  __bf16* Av = Ak + (size_t)M_ * E_;
  __bf16* Bq = Av + (size_t)M_ * E_;              // packed weights [1024,1024]
  __bf16* Bk = Bq + (size_t)E_ * E_;
  __bf16* Bv = Bk + (size_t)E_ * E_;
  __bf16* Bo = Bv + (size_t)E_ * E_;
  __bf16* qhb = Bo + (size_t)E_ * E_;             // [B,H,S,64]
  __bf16* khb = qhb + (size_t)8388608;
  __bf16* vTb = khb + (size_t)8388608;            // [B,H,64,S]
  __bf16* concat = Aq;  // reuse Aq region after projections are consumed

  // NOTE: grid.z > 1 dispatches silently did not execute in this harness
  // (round-4/5 forensics) — keep all grids 1-D/2-D. Round-10: qkv merge
  // cost ~11us — keep split. Round-14: attn grid stays (64 bh, 8 pr).
  // Round-15: cvt stays separate (reg-staged fusion regressed +6us).
  cvt_all<<<dim3(8192, 3), 256, 0, stream>>>(q, k, v, Aq, Ak, Av);
  pack_all<<<dim3(4096, 4), 256, 0, stream>>>(wq, wk, wv, wo, Bq, Bk, Bv, Bo);
  gemm_qk<<<dim3(64, 16), 256, 0, stream>>>(Aq, Ak, Bq, Bk, bq, bk, qhb, khb);
  gemm_bt<1><<<dim3(8, 64), 256, 0, stream>>>(Bv, Av, bv, vTb);
  attn_fused<<<dim3(64, 8), 256, 0, stream>>>(qhb, khb, vTb, concat, use_mask);
  gemm_bt<2><<<dim3(64, 8), 256, 0, stream>>>(concat, Bo, bo, d_out);
}

// Round 17
// 194.260 us; speedup vs baseline: 1.0628x; 1.0628x over previous
//
#include <hip/hip_runtime.h>

// Problem constants
#define B_ 4
#define S_ 2048
#define H_ 16
#define D_ 64
#define E_ 1024
#define M_ 8192   // B_*S_

typedef __attribute__((ext_vector_type(8))) __bf16 bf16x8;
typedef __attribute__((ext_vector_type(4))) __bf16 bf16x4;
typedef __attribute__((ext_vector_type(4))) float f32x4;
typedef __attribute__((ext_vector_type(16))) float f32x16;

// async global->LDS, 16B per lane; LDS base must be wave-uniform
__device__ __forceinline__ void gload_lds16(const void* g, void* l) {
  __builtin_amdgcn_global_load_lds(
      (const __attribute__((address_space(1))) unsigned int*)g,
      (__attribute__((address_space(3))) unsigned int*)l, 16, 0, 0);
}

__device__ __forceinline__ unsigned pk2(float a, float b) {
  union { __bf16 h; unsigned short u; } ua, ub;
  ua.h = (__bf16)a; ub.h = (__bf16)b;
  return ((unsigned)ub.u << 16) | (unsigned)ua.u;
}

// ---------------- fused cvt (y<3) + weight pack (y=3..6), one dispatch -----
// cvt body: round-12 cvt_all verbatim per y-slice. pack body: round-12
// pack_all verbatim with x<4096 guard (pack grid was (4096,4)).
__global__ void prep_all(const float* __restrict__ q, const float* __restrict__ k,
                         const float* __restrict__ v, const float* __restrict__ wq,
                         const float* __restrict__ wk, const float* __restrict__ wv,
                         const float* __restrict__ wo, __bf16* __restrict__ Aq,
                         __bf16* __restrict__ Ak, __bf16* __restrict__ Av,
                         __bf16* __restrict__ Bq, __bf16* __restrict__ Bk,
                         __bf16* __restrict__ Bv, __bf16* __restrict__ Bo) {
  const int y = blockIdx.y;
  if (y < 3) {
    const float* src = (y == 0) ? q : (y == 1) ? k : v;
    __bf16* dst = (y == 0) ? Aq : (y == 1) ? Ak : Av;
    const int i = blockIdx.x * blockDim.x + threadIdx.x;
    const float4 vv = ((const float4*)src)[i];
    bf16x4 o;
    o.x = (__bf16)vv.x; o.y = (__bf16)vv.y; o.z = (__bf16)vv.z; o.w = (__bf16)vv.w;
    ((bf16x4*)dst)[i] = o;
  } else {
    if (blockIdx.x >= 4096) return;
    const int yy = y - 3;
    const int idx = blockIdx.x * 256 + threadIdx.x;  // 1024*1024 total
    const int n = idx >> 10, kk = idx & 1023;
    if (yy < 3) {
      const float* w = (yy == 0) ? wq : (yy == 1) ? wk : wv;
      __bf16* out = (yy == 0) ? Bq : (yy == 1) ? Bk : Bv;
      out[idx] = (__bf16)w[((size_t)(n >> 6) << 16) + (kk << 6) + (n & 63)];
    } else {
      Bo[idx] = (__bf16)wo[((size_t)kk << 10) + n];
    }
  }
}

// ---------------- merged q+k projection GEMM (grid-y select, 2-D grid) -----
// Round-12 verbatim (single-buffer; round-16 forensics: double-buffer LDS
// 64KB halves occupancy and costs ~10us — inter-block TLP already hides
// staging at 32KB/4 blocks/CU).
__global__ __launch_bounds__(256) void gemm_qk(
    const __bf16* __restrict__ Aq, const __bf16* __restrict__ Ak,
    const __bf16* __restrict__ Bq, const __bf16* __restrict__ Bk,
    const float* __restrict__ bq, const float* __restrict__ bk,
    __bf16* __restrict__ qhb, __bf16* __restrict__ khb) {
  constexpr int K = 1024;
  __shared__ __bf16 As[128 * 64];
  __shared__ __bf16 Bs[128 * 64];
  const int t = threadIdx.x;
  const int w = t >> 6, l = t & 63;
  const int isK = blockIdx.y >> 3;
  const __bf16* A = isK ? Ak : Aq;
  const __bf16* Bt = isK ? Bk : Bq;
  const float* bias = isK ? bk : bq;
  __bf16* C = isK ? khb : qhb;
  const int m0 = blockIdx.x * 128, n0 = (blockIdx.y & 7) * 128;
  f32x4 acc[4][4] = {};

  for (int kt = 0; kt < K / 64; ++kt) {
    const int kb = kt * 64;
#pragma unroll
    for (int j = 0; j < 4; ++j) {
      const int ci = (j * 4 + w) * 64 + l;
      const int row = ci >> 3;
      const int c = (ci & 7) ^ (row & 7);
      gload_lds16(A + (size_t)(m0 + row) * K + kb + c * 8, As + (j * 4 + w) * 512);
      gload_lds16(Bt + (size_t)(n0 + row) * K + kb + c * 8, Bs + (j * 4 + w) * 512);
    }
    __syncthreads();
#pragma unroll
    for (int kk = 0; kk < 64; kk += 32) {
      bf16x8 af[4], bfr[4];
#pragma unroll
      for (int f = 0; f < 4; ++f) {
        const int ra = (w >> 1) * 64 + f * 16 + (l & 15);
        const int ca = ((kk >> 3) + (l >> 4)) ^ (ra & 7);
        af[f] = *(const bf16x8*)(As + ra * 64 + ca * 8);
        const int rb = (w & 1) * 64 + f * 16 + (l & 15);
        const int cb = ((kk >> 3) + (l >> 4)) ^ (rb & 7);
        bfr[f] = *(const bf16x8*)(Bs + rb * 64 + cb * 8);
      }
#pragma unroll
      for (int mf = 0; mf < 4; ++mf)
#pragma unroll
        for (int nf = 0; nf < 4; ++nf)
          acc[mf][nf] = __builtin_amdgcn_mfma_f32_16x16x32_bf16(af[mf], bfr[nf],
                                                                acc[mf][nf], 0, 0, 0);
    }
    __syncthreads();
  }

#pragma unroll
  for (int mf = 0; mf < 4; ++mf)
#pragma unroll
    for (int nf = 0; nf < 4; ++nf)
#pragma unroll
      for (int r = 0; r < 4; ++r) {
        const int gm = m0 + (w >> 1) * 64 + mf * 16 + (l >> 4) * 4 + r;
        const int gn = n0 + (w & 1) * 64 + nf * 16 + (l & 15);
        const float val = acc[mf][nf][r] + bias[gn];
        C[(((size_t)(gm >> 11) * H_ + (gn >> 6)) * S_ + (gm & 2047)) * D_ + (gn & 63)] =
            (__bf16)val;
      }
}

// ---------------- bf16 MFMA GEMM: C[M,N] = A[M,K] * Bt[N,K]^T + bias -------
// Round-12 verbatim. MODE 1: scatter bf16 to [B,H,D,S], bias[gm];
// MODE 2: fp32 C[gm*1024+gn] = acc + bias[gn]
template <int MODE>
__global__ __launch_bounds__(256) void gemm_bt(const __bf16* __restrict__ A,
                                               const __bf16* __restrict__ Bt,
                                               const float* __restrict__ bias,
                                               void* __restrict__ Cout) {
  constexpr int K = 1024;
  __shared__ __bf16 As[128 * 64];
  __shared__ __bf16 Bs[128 * 64];
  const int t = threadIdx.x;
  const int w = t >> 6, l = t & 63;
  const int m0 = blockIdx.x * 128, n0 = blockIdx.y * 128;
  f32x4 acc[4][4] = {};

  for (int kt = 0; kt < K / 64; ++kt) {
    const int kb = kt * 64;
#pragma unroll
    for (int j = 0; j < 4; ++j) {
      const int ci = (j * 4 + w) * 64 + l;
      const int row = ci >> 3;
      const int c = (ci & 7) ^ (row & 7);
      gload_lds16(A + (size_t)(m0 + row) * K + kb + c * 8, As + (j * 4 + w) * 512);
      gload_lds16(Bt + (size_t)(n0 + row) * K + kb + c * 8, Bs + (j * 4 + w) * 512);
    }
    __syncthreads();
#pragma unroll
    for (int kk = 0; kk < 64; kk += 32) {
      bf16x8 af[4], bfr[4];
#pragma unroll
      for (int f = 0; f < 4; ++f) {
        const int ra = (w >> 1) * 64 + f * 16 + (l & 15);
        const int ca = ((kk >> 3) + (l >> 4)) ^ (ra & 7);
        af[f] = *(const bf16x8*)(As + ra * 64 + ca * 8);
        const int rb = (w & 1) * 64 + f * 16 + (l & 15);
        const int cb = ((kk >> 3) + (l >> 4)) ^ (rb & 7);
        bfr[f] = *(const bf16x8*)(Bs + rb * 64 + cb * 8);
      }
#pragma unroll
      for (int mf = 0; mf < 4; ++mf)
#pragma unroll
        for (int nf = 0; nf < 4; ++nf)
          acc[mf][nf] = __builtin_amdgcn_mfma_f32_16x16x32_bf16(af[mf], bfr[nf],
                                                                acc[mf][nf], 0, 0, 0);
    }
    __syncthreads();
  }

#pragma unroll
  for (int mf = 0; mf < 4; ++mf) {
#pragma unroll
    for (int nf = 0; nf < 4; ++nf) {
#pragma unroll
      for (int r = 0; r < 4; ++r) {
        const int gm = m0 + (w >> 1) * 64 + mf * 16 + (l >> 4) * 4 + r;
        const int gn = n0 + (w & 1) * 64 + nf * 16 + (l & 15);
        const float val = acc[mf][nf][r] + ((MODE == 1) ? bias[gm] : bias[gn]);
        if constexpr (MODE == 1) {
          ((__bf16*)Cout)[(((size_t)(gn >> 11) * H_ + (gm >> 6)) * D_ + (gm & 63)) * S_ + (gn & 2047)] =
              (__bf16)val;
        } else {
          ((float*)Cout)[(size_t)gm * 1024 + gn] = val;
        }
      }
    }
  }
}

// ---------------- attn staging helpers -------------------------------------
__device__ __forceinline__ void stage_k128(const __bf16* __restrict__ Kb, int kt,
                                           __bf16* Kdst, int t, int w) {
#pragma unroll
  for (int j = 0; j < 4; ++j) {
    const int ci = j * 256 + t;
    const int row = ci >> 3;
    const int sc = (ci & 7) ^ (row & 7);
    gload_lds16(Kb + (size_t)(kt * 128 + row) * D_ + sc * 8, Kdst + j * 2048 + w * 512);
  }
}
__device__ __forceinline__ void stage_v64(const __bf16* __restrict__ Vb, int col0,
                                          __bf16* Vdst, int t, int w) {
#pragma unroll
  for (int j = 0; j < 2; ++j) {
    const int ci = j * 256 + t;
    const int row = ci >> 3;
    const int sc = (ci & 7) ^ (row & 7);
    gload_lds16(Vb + (size_t)row * S_ + col0 + sc * 8, Vdst + j * 2048 + w * 512);
  }
}

// ---------------- fused causal flash attention (v8, round-12 verbatim) -----
// grid (64 bh, 8 pr). Round-14 forensics: same-bh blocks are ids bh+64*pr,
// 64%8==0 -> same XCD -> K/V L2 locality. Do NOT swap the grid axes
// (tried: FETCH 27->147MB, +5us).
__global__ __launch_bounds__(256, 2) void attn_fused(const __bf16* __restrict__ qh,
                                                     const __bf16* __restrict__ kh,
                                                     const __bf16* __restrict__ vT,
                                                     __bf16* __restrict__ concat,
                                                     const int* __restrict__ use_mask_p) {
  __shared__ __bf16 Ks[2][128 * 64];     // [buf][kv 128][e 64]
  __shared__ __bf16 Vs[2][2][64 * 64];   // [buf][sub][e 64][kv 64]
  const int t = threadIdx.x, w = t >> 6, l = t & 63;
  const int lo = l & 31, hi = l >> 5;
  const int bh = blockIdx.x, pr = blockIdx.y;  // pr in 0..7
  const int usemask = *use_mask_p;
  const __bf16* Qb = qh + (size_t)bh * S_ * D_;
  const __bf16* Kb = kh + (size_t)bh * S_ * D_;
  const __bf16* Vb = vT + (size_t)bh * D_ * S_;
  const int b = bh >> 4, hh = bh & 15;
  constexpr float CEXP = 0.125f * 1.4426950408889634f;  // scale*log2(e)

  bf16x8 ones;
#pragma unroll
  for (int i = 0; i < 8; ++i) ones[i] = (__bf16)1.0f;

  int cur = 0;
  for (int half = 0; half < 2; ++half) {
    const int qt = half ? (15 - pr) : pr;       // 16 q-tiles of 128 rows
    const int qrow0 = qt * 128 + w * 32;
    const int nkt = usemask ? (qt + 1) : (S_ / 128);        // 128-kv steps
    const int ktw = usemask ? (2 * qt + (w >> 1)) : (1 << 30);  // 64-kv units

    // Q B-frags (col=lo, k=e contiguous 8 at hi*8), loop-invariant
    bf16x8 qf[4];
#pragma unroll
    for (int ks = 0; ks < 4; ++ks)
      qf[ks] = *(const bf16x8*)(Qb + (size_t)(qrow0 + lo) * D_ + ks * 16 + hi * 8);

    float m = -3e38f;
    f32x16 lsacc = {};
    f32x16 o0 = {}, o1 = {};

    // prologue: stage tile 0 into buf[cur]
    stage_k128(Kb, 0, &Ks[cur][0], t, w);
    stage_v64(Vb, 0, &Vs[cur][0][0], t, w);
    stage_v64(Vb, 64, &Vs[cur][1][0], t, w);

    for (int kt = 0; kt < nkt; ++kt) {
      __builtin_amdgcn_sched_barrier(0);
      asm volatile("s_waitcnt vmcnt(0)" ::: "memory");
      __builtin_amdgcn_s_barrier();
      __builtin_amdgcn_sched_barrier(0);

      // stage next 128-kv tile into the other buffer (overlaps this compute)
      if (kt + 1 < nkt) {
        const int nxt = cur ^ 1;
        stage_k128(Kb, kt + 1, &Ks[nxt][0], t, w);
        stage_v64(Vb, (kt + 1) * 128, &Vs[nxt][0][0], t, w);
        stage_v64(Vb, (kt + 1) * 128 + 64, &Vs[nxt][1][0], t, w);
      }

#pragma unroll
      for (int sub = 0; sub < 2; ++sub) {
        const int st = 2 * kt + sub;          // 64-kv sub-tile index
        if (st <= ktw) {
          const __bf16* Ksub = &Ks[cur][sub * 64 * 64];
          const __bf16* Vsub = &Vs[cur][sub][0];

          // ---- S^T = K * Q^T ----
          f32x16 s0 = {}, s1 = {};
          __builtin_amdgcn_s_setprio(1);
#pragma unroll
          for (int ks = 0; ks < 4; ++ks) {
            const int ch = ((ks << 1) | hi) ^ (lo & 7);
            const bf16x8 k0 = *(const bf16x8*)(Ksub + lo * 64 + ch * 8);
            const bf16x8 k1 = *(const bf16x8*)(Ksub + (32 + lo) * 64 + ch * 8);
            s0 = __builtin_amdgcn_mfma_f32_32x32x16_bf16(k0, qf[ks], s0, 0, 0, 0);
            s1 = __builtin_amdgcn_mfma_f32_32x32x16_bf16(k1, qf[ks], s1, 0, 0, 0);
          }
          __builtin_amdgcn_s_setprio(0);

          if (usemask && st == ktw) {  // diagonal sub-tile (raw-score mask)
            const int qloc = ((w & 1) << 5) + lo;
#pragma unroll
            for (int r = 0; r < 16; ++r) {
              const int kv0 = (r & 3) + 8 * (r >> 2) + 4 * hi;
              if (kv0 > qloc) s0[r] = -1e30f;
              if (kv0 + 32 > qloc) s1[r] = -1e30f;
            }
          }

          // ---- online softmax, lane-local; pair-shfl only when rescaling ----
          float pm = s0[0];
#pragma unroll
          for (int r = 1; r < 16; ++r) pm = fmaxf(pm, s0[r]);
#pragma unroll
          for (int r = 0; r < 16; ++r) pm = fmaxf(pm, s1[r]);

          if (!__all(pm - m <= 64.0f)) {  // defer-max (8 logit units)
            const float pmp = fmaxf(pm, __shfl_xor(pm, 32));  // pair-consistent
            const float mn = fmaxf(m, pmp);
            const float al = __builtin_amdgcn_exp2f((m - mn) * CEXP);
            m = mn;
            lsacc[0] *= al;
            o0 *= al;
            o1 *= al;
          }
          const float mneg = -m * CEXP;  // exp2(s*C - m*C) via fma

          // exp + pack into 4-value blocks (2 words each): W[mf][j]
          unsigned W0[4][2], W1[4][2];
#pragma unroll
          for (int j = 0; j < 4; ++j) {
            float p0 = __builtin_amdgcn_exp2f(__builtin_fmaf(s0[4 * j + 0], CEXP, mneg));
            float p1 = __builtin_amdgcn_exp2f(__builtin_fmaf(s0[4 * j + 1], CEXP, mneg));
            float p2 = __builtin_amdgcn_exp2f(__builtin_fmaf(s0[4 * j + 2], CEXP, mneg));
            float p3 = __builtin_amdgcn_exp2f(__builtin_fmaf(s0[4 * j + 3], CEXP, mneg));
            W0[j][0] = pk2(p0, p1);
            W0[j][1] = pk2(p2, p3);
            float q0 = __builtin_amdgcn_exp2f(__builtin_fmaf(s1[4 * j + 0], CEXP, mneg));
            float q1 = __builtin_amdgcn_exp2f(__builtin_fmaf(s1[4 * j + 1], CEXP, mneg));
            float q2 = __builtin_amdgcn_exp2f(__builtin_fmaf(s1[4 * j + 2], CEXP, mneg));
            float q3 = __builtin_amdgcn_exp2f(__builtin_fmaf(s1[4 * j + 3], CEXP, mneg));
            W1[j][0] = pk2(q0, q1);
            W1[j][1] = pk2(q2, q3);
          }

          // build P^T B-frags in-register: pairwise permlane32_swap (proven)
          bf16x8 pa[4];
#pragma unroll
          for (int ks = 0; ks < 4; ++ks) {
            const int c = ks & 1;
            unsigned x0, x1, y0, y1;
            if ((ks >> 1) == 0) {
              x0 = W0[2 * c][0]; x1 = W0[2 * c][1];
              y0 = W0[2 * c + 1][0]; y1 = W0[2 * c + 1][1];
            } else {
              x0 = W1[2 * c][0]; x1 = W1[2 * c][1];
              y0 = W1[2 * c + 1][0]; y1 = W1[2 * c + 1][1];
            }
            asm volatile("v_permlane32_swap_b32 %0, %1" : "+v"(x0), "+v"(y0));
            asm volatile("v_permlane32_swap_b32 %0, %1" : "+v"(x1), "+v"(y1));
            union { unsigned u[4]; bf16x8 v; } uu;
            uu.u[0] = x0; uu.u[1] = x1; uu.u[2] = y0; uu.u[3] = y1;
            pa[ks] = uu.v;
          }

          // ---- O^T += V^T * P^T ; ls += 1^T * P^T (column sums) ----
          __builtin_amdgcn_s_setprio(1);
#pragma unroll
          for (int ks = 0; ks < 4; ++ks) {
            const int ch = ((ks << 1) | hi) ^ (lo & 7);
            const bf16x8 v0 = *(const bf16x8*)(Vsub + lo * 64 + ch * 8);
            const bf16x8 v1 = *(const bf16x8*)(Vsub + (32 + lo) * 64 + ch * 8);
            o0 = __builtin_amdgcn_mfma_f32_32x32x16_bf16(v0, pa[ks], o0, 0, 0, 0);
            o1 = __builtin_amdgcn_mfma_f32_32x32x16_bf16(v1, pa[ks], o1, 0, 0, 0);
            lsacc = __builtin_amdgcn_mfma_f32_32x32x16_bf16(ones, pa[ks], lsacc, 0, 0, 0);
          }
          __builtin_amdgcn_s_setprio(0);
        }
      }
      cur ^= 1;
    }

    // epilogue: out[qrow][h*64 + e] = o^T[e][q]/ls  (ls = lsacc[0], col=q)
    const float inv = 1.0f / lsacc[0];
    const size_t rowbase = ((size_t)(b * S_ + qrow0 + lo)) * E_ + hh * 64;
#pragma unroll
    for (int rr = 0; rr < 4; ++rr) {
      bf16x4 v0, v1;
#pragma unroll
      for (int bb = 0; bb < 4; ++bb) {
        v0[bb] = (__bf16)(o0[4 * rr + bb] * inv);
        v1[bb] = (__bf16)(o1[4 * rr + bb] * inv);
      }
      *(bf16x4*)(concat + rowbase + 8 * rr + 4 * hi) = v0;
      *(bf16x4*)(concat + rowbase + 32 + 8 * rr + 4 * hi) = v1;
    }
  }
}

// ---------------- launch ----------------
extern "C" void kernel_launch(void* const* d_in, const int* in_sizes, int n_in,
                              void* d_out, int out_size, void* d_ws, size_t ws_size,
                              hipStream_t stream) {
  const float* q = (const float*)d_in[0];
  const float* k = (const float*)d_in[1];
  const float* v = (const float*)d_in[2];
  const float* wq = (const float*)d_in[3];
  const float* bq = (const float*)d_in[4];
  const float* wk = (const float*)d_in[5];
  const float* bk = (const float*)d_in[6];
  const float* wv = (const float*)d_in[7];
  const float* bv = (const float*)d_in[8];
  const float* wo = (const float*)d_in[9];
  const float* bo = (const float*)d_in[10];
  const int* use_mask = (const int*)d_in[11];
  (void)in_sizes; (void)n_in; (void)out_size; (void)ws_size;

  char* ws = (char*)d_ws;
  __bf16* Aq = (__bf16*)ws;                       // [8192,1024] bf16
  __bf16* Ak = Aq + (size_t)M_ * E_;
  __bf16* Av = Ak + (size_t)M_ * E_;
  __bf16* Bq = Av + (size_t)M_ * E_;              // packed weights [1024,1024]
  __bf16* Bk = Bq + (size_t)E_ * E_;
  __bf16* Bv = Bk + (size_t)E_ * E_;
  __bf16* Bo = Bv + (size_t)E_ * E_;
  __bf16* qhb = Bo + (size_t)E_ * E_;             // [B,H,S,64]
  __bf16* khb = qhb + (size_t)8388608;
  __bf16* vTb = khb + (size_t)8388608;            // [B,H,64,S]
  __bf16* concat = Aq;  // reuse Aq region after projections are consumed

  // Forensics ledger: grid.z>1 silently no-ops (r4/5) — 1-D/2-D grids only.
  // qkv GEMM merge +11us (r10) — keep split. attn grid stays (64 bh, 8 pr)
  // (r14: swap costs FETCH 27->147MB). cvt fusion into GEMM +6us (r15).
  // GEMM LDS double-buffer +10us (r16) — keep single-buffer 32KB.
  prep_all<<<dim3(8192, 7), 256, 0, stream>>>(q, k, v, wq, wk, wv, wo,
                                              Aq, Ak, Av, Bq, Bk, Bv, Bo);
  gemm_qk<<<dim3(64, 16), 256, 0, stream>>>(Aq, Ak, Bq, Bk, bq, bk, qhb, khb);
  gemm_bt<1><<<dim3(8, 64), 256, 0, stream>>>(Bv, Av, bv, vTb);
  attn_fused<<<dim3(64, 8), 256, 0, stream>>>(qhb, khb, vTb, concat, use_mask);
  gemm_bt<2><<<dim3(64, 8), 256, 0, stream>>>(concat, Bo, bo, d_out);
}

// Round 18
// 194.242 us; speedup vs baseline: 1.0629x; 1.0001x over previous
//
#include <hip/hip_runtime.h>

// Problem constants
#define B_ 4
#define S_ 2048
#define H_ 16
#define D_ 64
#define E_ 1024
#define M_ 8192   // B_*S_

typedef __attribute__((ext_vector_type(8))) __bf16 bf16x8;
typedef __attribute__((ext_vector_type(4))) __bf16 bf16x4;
typedef __attribute__((ext_vector_type(4))) float f32x4;
typedef __attribute__((ext_vector_type(16))) float f32x16;

#define CEXPF (0.125f * 1.4426950408889634f)  // attn scale * log2(e)

// async global->LDS, 16B per lane; LDS base must be wave-uniform
__device__ __forceinline__ void gload_lds16(const void* g, void* l) {
  __builtin_amdgcn_global_load_lds(
      (const __attribute__((address_space(1))) unsigned int*)g,
      (__attribute__((address_space(3))) unsigned int*)l, 16, 0, 0);
}

__device__ __forceinline__ unsigned pk2(float a, float b) {
  union { __bf16 h; unsigned short u; } ua, ub;
  ua.h = (__bf16)a; ub.h = (__bf16)b;
  return ((unsigned)ub.u << 16) | (unsigned)ua.u;
}

// ---------------- fused cvt (y<3) + weight pack (y=3..6), one dispatch -----
__global__ void prep_all(const float* __restrict__ q, const float* __restrict__ k,
                         const float* __restrict__ v, const float* __restrict__ wq,
                         const float* __restrict__ wk, const float* __restrict__ wv,
                         const float* __restrict__ wo, __bf16* __restrict__ Aq,
                         __bf16* __restrict__ Ak, __bf16* __restrict__ Av,
                         __bf16* __restrict__ Bq, __bf16* __restrict__ Bk,
                         __bf16* __restrict__ Bv, __bf16* __restrict__ Bo) {
  const int y = blockIdx.y;
  if (y < 3) {
    const float* src = (y == 0) ? q : (y == 1) ? k : v;
    __bf16* dst = (y == 0) ? Aq : (y == 1) ? Ak : Av;
    const int i = blockIdx.x * blockDim.x + threadIdx.x;
    const float4 vv = ((const float4*)src)[i];
    bf16x4 o;
    o.x = (__bf16)vv.x; o.y = (__bf16)vv.y; o.z = (__bf16)vv.z; o.w = (__bf16)vv.w;
    ((bf16x4*)dst)[i] = o;
  } else {
    if (blockIdx.x >= 4096) return;
    const int yy = y - 3;
    const int idx = blockIdx.x * 256 + threadIdx.x;  // 1024*1024 total
    const int n = idx >> 10, kk = idx & 1023;
    if (yy < 3) {
      const float* w = (yy == 0) ? wq : (yy == 1) ? wk : wv;
      __bf16* out = (yy == 0) ? Bq : (yy == 1) ? Bk : Bv;
      out[idx] = (__bf16)w[((size_t)(n >> 6) << 16) + (kk << 6) + (n & 63)];
    } else {
      Bo[idx] = (__bf16)wo[((size_t)kk << 10) + n];
    }
  }
}

// ---------------- merged q+k projection GEMM (grid-y select, 2-D grid) -----
__global__ __launch_bounds__(256) void gemm_qk(
    const __bf16* __restrict__ Aq, const __bf16* __restrict__ Ak,
    const __bf16* __restrict__ Bq, const __bf16* __restrict__ Bk,
    const float* __restrict__ bq, const float* __restrict__ bk,
    __bf16* __restrict__ qhb, __bf16* __restrict__ khb) {
  constexpr int K = 1024;
  __shared__ __bf16 As[128 * 64];
  __shared__ __bf16 Bs[128 * 64];
  const int t = threadIdx.x;
  const int w = t >> 6, l = t & 63;
  const int isK = blockIdx.y >> 3;
  const __bf16* A = isK ? Ak : Aq;
  const __bf16* Bt = isK ? Bk : Bq;
  const float* bias = isK ? bk : bq;
  __bf16* C = isK ? khb : qhb;
  const int m0 = blockIdx.x * 128, n0 = (blockIdx.y & 7) * 128;
  f32x4 acc[4][4] = {};

  for (int kt = 0; kt < K / 64; ++kt) {
    const int kb = kt * 64;
#pragma unroll
    for (int j = 0; j < 4; ++j) {
      const int ci = (j * 4 + w) * 64 + l;
      const int row = ci >> 3;
      const int c = (ci & 7) ^ (row & 7);
      gload_lds16(A + (size_t)(m0 + row) * K + kb + c * 8, As + (j * 4 + w) * 512);
      gload_lds16(Bt + (size_t)(n0 + row) * K + kb + c * 8, Bs + (j * 4 + w) * 512);
    }
    __syncthreads();
#pragma unroll
    for (int kk = 0; kk < 64; kk += 32) {
      bf16x8 af[4], bfr[4];
#pragma unroll
      for (int f = 0; f < 4; ++f) {
        const int ra = (w >> 1) * 64 + f * 16 + (l & 15);
        const int ca = ((kk >> 3) + (l >> 4)) ^ (ra & 7);
        af[f] = *(const bf16x8*)(As + ra * 64 + ca * 8);
        const int rb = (w & 1) * 64 + f * 16 + (l & 15);
        const int cb = ((kk >> 3) + (l >> 4)) ^ (rb & 7);
        bfr[f] = *(const bf16x8*)(Bs + rb * 64 + cb * 8);
      }
#pragma unroll
      for (int mf = 0; mf < 4; ++mf)
#pragma unroll
        for (int nf = 0; nf < 4; ++nf)
          acc[mf][nf] = __builtin_amdgcn_mfma_f32_16x16x32_bf16(af[mf], bfr[nf],
                                                                acc[mf][nf], 0, 0, 0);
    }
    __syncthreads();
  }

#pragma unroll
  for (int mf = 0; mf < 4; ++mf)
#pragma unroll
    for (int nf = 0; nf < 4; ++nf)
#pragma unroll
      for (int r = 0; r < 4; ++r) {
        const int gm = m0 + (w >> 1) * 64 + mf * 16 + (l >> 4) * 4 + r;
        const int gn = n0 + (w & 1) * 64 + nf * 16 + (l & 15);
        const float val = acc[mf][nf][r] + bias[gn];
        C[(((size_t)(gm >> 11) * H_ + (gn >> 6)) * S_ + (gm & 2047)) * D_ + (gn & 63)] =
            (__bf16)val;
      }
}

// ---------------- bf16 MFMA GEMM: C[M,N] = A[M,K] * Bt[N,K]^T + bias -------
template <int MODE>
__global__ __launch_bounds__(256) void gemm_bt(const __bf16* __restrict__ A,
                                               const __bf16* __restrict__ Bt,
                                               const float* __restrict__ bias,
                                               void* __restrict__ Cout) {
  constexpr int K = 1024;
  __shared__ __bf16 As[128 * 64];
  __shared__ __bf16 Bs[128 * 64];
  const int t = threadIdx.x;
  const int w = t >> 6, l = t & 63;
  const int m0 = blockIdx.x * 128, n0 = blockIdx.y * 128;
  f32x4 acc[4][4] = {};

  for (int kt = 0; kt < K / 64; ++kt) {
    const int kb = kt * 64;
#pragma unroll
    for (int j = 0; j < 4; ++j) {
      const int ci = (j * 4 + w) * 64 + l;
      const int row = ci >> 3;
      const int c = (ci & 7) ^ (row & 7);
      gload_lds16(A + (size_t)(m0 + row) * K + kb + c * 8, As + (j * 4 + w) * 512);
      gload_lds16(Bt + (size_t)(n0 + row) * K + kb + c * 8, Bs + (j * 4 + w) * 512);
    }
    __syncthreads();
#pragma unroll
    for (int kk = 0; kk < 64; kk += 32) {
      bf16x8 af[4], bfr[4];
#pragma unroll
      for (int f = 0; f < 4; ++f) {
        const int ra = (w >> 1) * 64 + f * 16 + (l & 15);
        const int ca = ((kk >> 3) + (l >> 4)) ^ (ra & 7);
        af[f] = *(const bf16x8*)(As + ra * 64 + ca * 8);
        const int rb = (w & 1) * 64 + f * 16 + (l & 15);
        const int cb = ((kk >> 3) + (l >> 4)) ^ (rb & 7);
        bfr[f] = *(const bf16x8*)(Bs + rb * 64 + cb * 8);
      }
#pragma unroll
      for (int mf = 0; mf < 4; ++mf)
#pragma unroll
        for (int nf = 0; nf < 4; ++nf)
          acc[mf][nf] = __builtin_amdgcn_mfma_f32_16x16x32_bf16(af[mf], bfr[nf],
                                                                acc[mf][nf], 0, 0, 0);
    }
    __syncthreads();
  }

#pragma unroll
  for (int mf = 0; mf < 4; ++mf) {
#pragma unroll
    for (int nf = 0; nf < 4; ++nf) {
#pragma unroll
      for (int r = 0; r < 4; ++r) {
        const int gm = m0 + (w >> 1) * 64 + mf * 16 + (l >> 4) * 4 + r;
        const int gn = n0 + (w & 1) * 64 + nf * 16 + (l & 15);
        const float val = acc[mf][nf][r] + ((MODE == 1) ? bias[gm] : bias[gn]);
        if constexpr (MODE == 1) {
          ((__bf16*)Cout)[(((size_t)(gn >> 11) * H_ + (gm >> 6)) * D_ + (gm & 63)) * S_ + (gn & 2047)] =
              (__bf16)val;
        } else {
          ((float*)Cout)[(size_t)gm * 1024 + gn] = val;
        }
      }
    }
  }
}

// ---------------- attn staging helpers -------------------------------------
__device__ __forceinline__ void stage_k128(const __bf16* __restrict__ Kb, int kt,
                                           __bf16* Kdst, int t, int w) {
#pragma unroll
  for (int j = 0; j < 4; ++j) {
    const int ci = j * 256 + t;
    const int row = ci >> 3;
    const int sc = (ci & 7) ^ (row & 7);
    gload_lds16(Kb + (size_t)(kt * 128 + row) * D_ + sc * 8, Kdst + j * 2048 + w * 512);
  }
}
__device__ __forceinline__ void stage_v64(const __bf16* __restrict__ Vb, int col0,
                                          __bf16* Vdst, int t, int w) {
#pragma unroll
  for (int j = 0; j < 2; ++j) {
    const int ci = j * 256 + t;
    const int row = ci >> 3;
    const int sc = (ci & 7) ^ (row & 7);
    gload_lds16(Vb + (size_t)row * S_ + col0 + sc * 8, Vdst + j * 2048 + w * 512);
  }
}

// ---------------- v8 sub-tile body as inlined helper (per q-tile state) ----
__device__ __forceinline__ void attn_subtile(const __bf16* __restrict__ Ksub,
                                             const __bf16* __restrict__ Vsub,
                                             const bf16x8* qf, const bf16x8 ones,
                                             int lo, int hi, int qloc, bool diag,
                                             float& m, f32x16& lsacc,
                                             f32x16& o0, f32x16& o1) {
  // ---- S^T = K * Q^T ----
  f32x16 s0 = {}, s1 = {};
  __builtin_amdgcn_s_setprio(1);
#pragma unroll
  for (int ks = 0; ks < 4; ++ks) {
    const int ch = ((ks << 1) | hi) ^ (lo & 7);
    const bf16x8 k0 = *(const bf16x8*)(Ksub + lo * 64 + ch * 8);
    const bf16x8 k1 = *(const bf16x8*)(Ksub + (32 + lo) * 64 + ch * 8);
    s0 = __builtin_amdgcn_mfma_f32_32x32x16_bf16(k0, qf[ks], s0, 0, 0, 0);
    s1 = __builtin_amdgcn_mfma_f32_32x32x16_bf16(k1, qf[ks], s1, 0, 0, 0);
  }
  __builtin_amdgcn_s_setprio(0);

  if (diag) {  // triangular mask on diagonal sub-tile (raw scores)
#pragma unroll
    for (int r = 0; r < 16; ++r) {
      const int kv0 = (r & 3) + 8 * (r >> 2) + 4 * hi;
      if (kv0 > qloc) s0[r] = -1e30f;
      if (kv0 + 32 > qloc) s1[r] = -1e30f;
    }
  }

  // ---- online softmax, lane-local; pair-shfl only when rescaling ----
  float pm = s0[0];
#pragma unroll
  for (int r = 1; r < 16; ++r) pm = fmaxf(pm, s0[r]);
#pragma unroll
  for (int r = 0; r < 16; ++r) pm = fmaxf(pm, s1[r]);

  if (!__all(pm - m <= 64.0f)) {  // defer-max (8 logit units)
    const float pmp = fmaxf(pm, __shfl_xor(pm, 32));  // pair-consistent
    const float mn = fmaxf(m, pmp);
    const float al = __builtin_amdgcn_exp2f((m - mn) * CEXPF);
    m = mn;
    lsacc[0] *= al;
    o0 *= al;
    o1 *= al;
  }
  const float mneg = -m * CEXPF;  // exp2(s*C - m*C) via fma

  // exp + pack into 4-value blocks (2 words each): W[mf][j]
  unsigned W0[4][2], W1[4][2];
#pragma unroll
  for (int j = 0; j < 4; ++j) {
    float p0 = __builtin_amdgcn_exp2f(__builtin_fmaf(s0[4 * j + 0], CEXPF, mneg));
    float p1 = __builtin_amdgcn_exp2f(__builtin_fmaf(s0[4 * j + 1], CEXPF, mneg));
    float p2 = __builtin_amdgcn_exp2f(__builtin_fmaf(s0[4 * j + 2], CEXPF, mneg));
    float p3 = __builtin_amdgcn_exp2f(__builtin_fmaf(s0[4 * j + 3], CEXPF, mneg));
    W0[j][0] = pk2(p0, p1);
    W0[j][1] = pk2(p2, p3);
    float q0 = __builtin_amdgcn_exp2f(__builtin_fmaf(s1[4 * j + 0], CEXPF, mneg));
    float q1 = __builtin_amdgcn_exp2f(__builtin_fmaf(s1[4 * j + 1], CEXPF, mneg));
    float q2 = __builtin_amdgcn_exp2f(__builtin_fmaf(s1[4 * j + 2], CEXPF, mneg));
    float q3 = __builtin_amdgcn_exp2f(__builtin_fmaf(s1[4 * j + 3], CEXPF, mneg));
    W1[j][0] = pk2(q0, q1);
    W1[j][1] = pk2(q2, q3);
  }

  // build P^T B-frags in-register: pairwise permlane32_swap (proven)
  bf16x8 pa[4];
#pragma unroll
  for (int ks = 0; ks < 4; ++ks) {
    const int c = ks & 1;
    unsigned x0, x1, y0, y1;
    if ((ks >> 1) == 0) {
      x0 = W0[2 * c][0]; x1 = W0[2 * c][1];
      y0 = W0[2 * c + 1][0]; y1 = W0[2 * c + 1][1];
    } else {
      x0 = W1[2 * c][0]; x1 = W1[2 * c][1];
      y0 = W1[2 * c + 1][0]; y1 = W1[2 * c + 1][1];
    }
    asm volatile("v_permlane32_swap_b32 %0, %1" : "+v"(x0), "+v"(y0));
    asm volatile("v_permlane32_swap_b32 %0, %1" : "+v"(x1), "+v"(y1));
    union { unsigned u[4]; bf16x8 v; } uu;
    uu.u[0] = x0; uu.u[1] = x1; uu.u[2] = y0; uu.u[3] = y1;
    pa[ks] = uu.v;
  }

  // ---- O^T += V^T * P^T ; ls += 1^T * P^T (column sums) ----
  __builtin_amdgcn_s_setprio(1);
#pragma unroll
  for (int ks = 0; ks < 4; ++ks) {
    const int ch = ((ks << 1) | hi) ^ (lo & 7);
    const bf16x8 v0 = *(const bf16x8*)(Vsub + lo * 64 + ch * 8);
    const bf16x8 v1 = *(const bf16x8*)(Vsub + (32 + lo) * 64 + ch * 8);
    o0 = __builtin_amdgcn_mfma_f32_32x32x16_bf16(v0, pa[ks], o0, 0, 0, 0);
    o1 = __builtin_amdgcn_mfma_f32_32x32x16_bf16(v1, pa[ks], o1, 0, 0, 0);
    lsacc = __builtin_amdgcn_mfma_f32_32x32x16_bf16(ones, pa[ks], lsacc, 0, 0, 0);
  }
  __builtin_amdgcn_s_setprio(0);
}

// ---------------- fused causal flash attention (v10: merged kv sweep) ------
// One kv sweep serves BOTH q-tiles (A=pr, B=15-pr; range(A) ⊆ range(B)):
// stage+barrier rounds drop 17 -> 9..16/block, K/V frag reads shared while
// both tiles active. Sub-tile body = v8 verbatim (attn_subtile). Grid stays
// (64 bh, 8 pr): same-bh co-resident pairs share the identical kv stream.
__global__ __launch_bounds__(256, 2) void attn_fused(const __bf16* __restrict__ qh,
                                                     const __bf16* __restrict__ kh,
                                                     const __bf16* __restrict__ vT,
                                                     __bf16* __restrict__ concat,
                                                     const int* __restrict__ use_mask_p) {
  __shared__ __bf16 Ks[2][128 * 64];     // [buf][kv 128][e 64]
  __shared__ __bf16 Vs[2][2][64 * 64];   // [buf][sub][e 64][kv 64]
  const int t = threadIdx.x, w = t >> 6, l = t & 63;
  const int lo = l & 31, hi = l >> 5;
  const int bh = blockIdx.x, pr = blockIdx.y;  // pr in 0..7
  const int usemask = *use_mask_p;
  const __bf16* Qb = qh + (size_t)bh * S_ * D_;
  const __bf16* Kb = kh + (size_t)bh * S_ * D_;
  const __bf16* Vb = vT + (size_t)bh * D_ * S_;
  const int b = bh >> 4, hh = bh & 15;
  const int qloc = ((w & 1) << 5) + lo;

  bf16x8 ones;
#pragma unroll
  for (int i = 0; i < 8; ++i) ones[i] = (__bf16)1.0f;

  const int qtA = pr, qtB = 15 - pr;
  const int qrow0A = qtA * 128 + w * 32, qrow0B = qtB * 128 + w * 32;
  const int nkt = usemask ? (qtB + 1) : (S_ / 128);  // B's 128-kv tile count
  const int ktwA = usemask ? (2 * qtA + (w >> 1)) : (1 << 30);
  const int ktwB = usemask ? (2 * qtB + (w >> 1)) : (1 << 30);

  // Q B-frags for both q-tiles (col=lo, k=e contiguous 8 at hi*8)
  bf16x8 qfA[4], qfB[4];
#pragma unroll
  for (int ks = 0; ks < 4; ++ks) {
    qfA[ks] = *(const bf16x8*)(Qb + (size_t)(qrow0A + lo) * D_ + ks * 16 + hi * 8);
    qfB[ks] = *(const bf16x8*)(Qb + (size_t)(qrow0B + lo) * D_ + ks * 16 + hi * 8);
  }

  float mA = -3e38f, mB = -3e38f;
  f32x16 lsA = {}, lsB = {};
  f32x16 oA0 = {}, oA1 = {}, oB0 = {}, oB1 = {};

  // prologue: stage tile 0 into buf 0
  int cur = 0;
  stage_k128(Kb, 0, &Ks[0][0], t, w);
  stage_v64(Vb, 0, &Vs[0][0][0], t, w);
  stage_v64(Vb, 64, &Vs[0][1][0], t, w);

  for (int kt = 0; kt < nkt; ++kt) {
    __builtin_amdgcn_sched_barrier(0);
    asm volatile("s_waitcnt vmcnt(0)" ::: "memory");
    __builtin_amdgcn_s_barrier();
    __builtin_amdgcn_sched_barrier(0);

    // stage next 128-kv tile into the other buffer (overlaps this compute)
    if (kt + 1 < nkt) {
      const int nxt = cur ^ 1;
      stage_k128(Kb, kt + 1, &Ks[nxt][0], t, w);
      stage_v64(Vb, (kt + 1) * 128, &Vs[nxt][0][0], t, w);
      stage_v64(Vb, (kt + 1) * 128 + 64, &Vs[nxt][1][0], t, w);
    }

#pragma unroll
    for (int sub = 0; sub < 2; ++sub) {
      const int st = 2 * kt + sub;          // 64-kv sub-tile index
      const __bf16* Ksub = &Ks[cur][sub * 64 * 64];
      const __bf16* Vsub = &Vs[cur][sub][0];
      if (st <= ktwA)
        attn_subtile(Ksub, Vsub, qfA, ones, lo, hi, qloc,
                     usemask && st == ktwA, mA, lsA, oA0, oA1);
      if (st <= ktwB)
        attn_subtile(Ksub, Vsub, qfB, ones, lo, hi, qloc,
                     usemask && st == ktwB, mB, lsB, oB0, oB1);
    }
    cur ^= 1;
  }

  // epilogue: out[qrow][h*64 + e] = o^T[e][q]/ls  (ls = lsacc[0], col=q)
  {
    const float invA = 1.0f / lsA[0], invB = 1.0f / lsB[0];
    const size_t rbA = ((size_t)(b * S_ + qrow0A + lo)) * E_ + hh * 64;
    const size_t rbB = ((size_t)(b * S_ + qrow0B + lo)) * E_ + hh * 64;
#pragma unroll
    for (int rr = 0; rr < 4; ++rr) {
      bf16x4 a0, a1, b0, b1;
#pragma unroll
      for (int bb = 0; bb < 4; ++bb) {
        a0[bb] = (__bf16)(oA0[4 * rr + bb] * invA);
        a1[bb] = (__bf16)(oA1[4 * rr + bb] * invA);
        b0[bb] = (__bf16)(oB0[4 * rr + bb] * invB);
        b1[bb] = (__bf16)(oB1[4 * rr + bb] * invB);
      }
      *(bf16x4*)(concat + rbA + 8 * rr + 4 * hi) = a0;
      *(bf16x4*)(concat + rbA + 32 + 8 * rr + 4 * hi) = a1;
      *(bf16x4*)(concat + rbB + 8 * rr + 4 * hi) = b0;
      *(bf16x4*)(concat + rbB + 32 + 8 * rr + 4 * hi) = b1;
    }
  }
}

// ---------------- launch ----------------
extern "C" void kernel_launch(void* const* d_in, const int* in_sizes, int n_in,
                              void* d_out, int out_size, void* d_ws, size_t ws_size,
                              hipStream_t stream) {
  const float* q = (const float*)d_in[0];
  const float* k = (const float*)d_in[1];
  const float* v = (const float*)d_in[2];
  const float* wq = (const float*)d_in[3];
  const float* bq = (const float*)d_in[4];
  const float* wk = (const float*)d_in[5];
  const float* bk = (const float*)d_in[6];
  const float* wv = (const float*)d_in[7];
  const float* bv = (const float*)d_in[8];
  const float* wo = (const float*)d_in[9];
  const float* bo = (const float*)d_in[10];
  const int* use_mask = (const int*)d_in[11];
  (void)in_sizes; (void)n_in; (void)out_size; (void)ws_size;

  char* ws = (char*)d_ws;
  __bf16* Aq = (__bf16*)ws;                       // [8192,1024] bf16
  __bf16* Ak = Aq + (size_t)M_ * E_;
  __bf16* Av = Ak + (size_t)M_ * E_;
  __bf16* Bq = Av + (size_t)M_ * E_;              // packed weights [1024,1024]
  __bf16* Bk = Bq + (size_t)E_ * E_;
  __bf16* Bv = Bk + (size_t)E_ * E_;
  __bf16* Bo = Bv + (size_t)E_ * E_;
  __bf16* qhb = Bo + (size_t)E_ * E_;             // [B,H,S,64]
  __bf16* khb = qhb + (size_t)8388608;
  __bf16* vTb = khb + (size_t)8388608;            // [B,H,64,S]
  __bf16* concat = Aq;  // reuse Aq region after projections are consumed

  // Forensics ledger: grid.z>1 silently no-ops (r4/5) — 1-D/2-D grids only.
  // qkv GEMM merge +11us (r10) — keep split. attn grid stays (64 bh, 8 pr)
  // (r14: swap costs FETCH 27->147MB). cvt fusion into GEMM +6us (r15).
  // GEMM LDS double-buffer +10us (r16) — keep single-buffer 32KB.
  prep_all<<<dim3(8192, 7), 256, 0, stream>>>(q, k, v, wq, wk, wv, wo,
                                              Aq, Ak, Av, Bq, Bk, Bv, Bo);
  gemm_qk<<<dim3(64, 16), 256, 0, stream>>>(Aq, Ak, Bq, Bk, bq, bk, qhb, khb);
  gemm_bt<1><<<dim3(8, 64), 256, 0, stream>>>(Bv, Av, bv, vTb);
  attn_fused<<<dim3(64, 8), 256, 0, stream>>>(qhb, khb, vTb, concat, use_mask);
  gemm_bt<2><<<dim3(64, 8), 256, 0, stream>>>(concat, Bo, bo, d_out);
}